// Round 6
// baseline (516.911 us; speedup 1.0000x reference)
//
#include <hip/hip_runtime.h>
#include <hip/hip_bf16.h>
#include <math.h>

#define BATCH 32
#define NTOK 577
#define NPATCH 576
#define CDIM 768
#define HEADS 12
#define DHEAD 64
#define W3 2304
#define FT 404
#define GRID 512   // 2 blocks/CU guaranteed co-resident (LDS 36.9K -> <=4/CU, VGPR cap 256 -> >=2/CU)

// ---- workspace layout (float offsets) ----
#define WS_WTIL  24576      // 32*12*768
#define WS_DBIAS 319488     // 32*12
#define WS_DOTS  319872     // 32*12*577
#define WS_IND   541440     // 32*404 (as int)
#define WS_BAR   600000     // 4 unsigned barrier counters (zeroed via memset node)

// ---- output layout (FLOAT32 element offsets; d_out is float*) ----
#define O_X      0ULL           // 32*577*768 = 14180352
#define O_INDEX  14180352ULL    // 32*404*768 = 9928704
#define O_IND    24109056ULL    // 32*404
#define O_CA     24121984ULL    // 32*576
#define O_FT     24140416ULL

union SmemU {
    struct { float x0s[CDIM]; float red[256]; float qs[DHEAD]; } p1;      // 4.3 KB
    struct { float wt[HEADS * CDIM]; float db[HEADS]; } p2;               // 36.9 KB (max)
    struct { float dl[HEADS * NTOK]; float mh[HEADS]; float sh[HEADS];
             unsigned int vals[NPATCH]; int wsum[4]; } p3;                // 30.1 KB
};

// Device-scope grid barrier: release-add, acquire-spin. Counters pre-zeroed.
__device__ __forceinline__ void grid_barrier(unsigned* ctr) {
    __syncthreads();
    if (threadIdx.x == 0) {
        __threadfence();                       // release prior writes at device scope
        atomicAdd(ctr, 1u);                    // device-scope by default on CDNA
        while (__hip_atomic_load(ctr, __ATOMIC_ACQUIRE, __HIP_MEMORY_SCOPE_AGENT) < GRID) {
            __builtin_amdgcn_s_sleep(1);
        }
    }
    __syncthreads();
}

__global__ __launch_bounds__(256, 2) void k_all(const float* __restrict__ x,
                                                const float* __restrict__ W,
                                                const float* __restrict__ bias,
                                                float* __restrict__ ws,
                                                float* __restrict__ out,
                                                int write_ft) {
    __shared__ SmemU sm;
    const int u = blockIdx.x, tid = threadIdx.x;
    const int w = tid >> 6, lane = tid & 63;

    float* wtil  = ws + WS_WTIL;
    float* dbias = ws + WS_DBIAS;
    float* dots  = ws + WS_DOTS;
    int*   indw  = (int*)(ws + WS_IND);
    unsigned* bar = (unsigned*)(ws + WS_BAR);

    // ---------------- P1: fold (q = x0·Wq + bq; wtil = q·Wk^T; dbias = q·bk) ----------------
    if (u < BATCH * HEADS) {
        const int b = u / HEADS, h = u % HEADS;
        for (int i = tid; i < CDIM; i += 256) sm.p1.x0s[i] = x[(size_t)b * NTOK * CDIM + i];
        __syncthreads();
        {
            const int d = tid & 63, seg = tid >> 6;
            const float* Wq = W + (size_t)(h * DHEAD + d);
            float acc = 0.f;
            const int c0 = seg * 192;
            #pragma unroll 8
            for (int c = c0; c < c0 + 192; c++)
                acc += sm.p1.x0s[c] * Wq[(size_t)c * W3];
            sm.p1.red[tid] = acc;
        }
        __syncthreads();
        if (tid < DHEAD) {
            float q = sm.p1.red[tid] + sm.p1.red[tid + 64] + sm.p1.red[tid + 128]
                    + sm.p1.red[tid + 192] + bias[h * DHEAD + tid];
            sm.p1.qs[tid] = q;
            float t = q * bias[CDIM + h * DHEAD + tid];
            #pragma unroll
            for (int off = 32; off; off >>= 1) t += __shfl_down(t, off);
            if (tid == 0) dbias[b * HEADS + h] = t;
        }
        __syncthreads();
        for (int c = tid; c < CDIM; c += 256) {
            const float* wr = W + (size_t)c * W3 + CDIM + h * DHEAD;
            float acc = 0.f;
            #pragma unroll
            for (int d = 0; d < DHEAD; d += 4) {
                float4 a = *reinterpret_cast<const float4*>(wr + d);
                acc += a.x * sm.p1.qs[d] + a.y * sm.p1.qs[d + 1]
                     + a.z * sm.p1.qs[d + 2] + a.w * sm.p1.qs[d + 3];
            }
            wtil[((size_t)b * HEADS + h) * CDIM + c] = acc;
        }
    }
    grid_barrier(bar + 0);

    // ---------------- P2: dots[b,h,j] + fused x -> out0 copy ----------------
    {
        const int b = u >> 4, c4 = (u & 15) * 4 + w;   // c4 in [0,64): token-slot within 64-stride
        for (int i = tid; i < HEADS * CDIM; i += 256) sm.p2.wt[i] = wtil[(size_t)b * HEADS * CDIM + i];
        if (tid < HEADS) sm.p2.db[tid] = dbias[b * HEADS + tid];
        __syncthreads();
        for (int it = 0; it < 10; it++) {
            const int j = it * 64 + c4;
            if (j >= NTOK) break;                       // j monotone in it
            const float4* xp = reinterpret_cast<const float4*>(x + ((size_t)b * NTOK + j) * CDIM);
            float4* op = reinterpret_cast<float4*>(out + O_X + ((size_t)b * NTOK + j) * CDIM);
            float acc[HEADS];
            #pragma unroll
            for (int h = 0; h < HEADS; h++) acc[h] = 0.f;
            #pragma unroll
            for (int i = 0; i < 3; i++) {
                float4 a = xp[i * 64 + lane];
                op[i * 64 + lane] = a;
                const int cbase = i * 256 + lane * 4;
                #pragma unroll
                for (int h = 0; h < HEADS; h++) {
                    float4 wv = *reinterpret_cast<const float4*>(&sm.p2.wt[h * CDIM + cbase]);
                    acc[h] += a.x * wv.x + a.y * wv.y + a.z * wv.z + a.w * wv.w;
                }
            }
            #pragma unroll
            for (int off = 32; off; off >>= 1)
                #pragma unroll
                for (int h = 0; h < HEADS; h++) acc[h] += __shfl_xor(acc[h], off);
            if (lane == 0) {
                #pragma unroll
                for (int h = 0; h < HEADS; h++)
                    dots[((size_t)b * HEADS + h) * NTOK + j] = 0.125f * (acc[h] + sm.p2.db[h]);
            }
        }
    }
    grid_barrier(bar + 1);

    // ---------------- P3: softmax stats + class_attention + top-404 + compact ----------------
    if (u < BATCH) {
        const int b = u;
        float* dl = sm.p3.dl;
        for (int i = tid; i < HEADS * NTOK; i += 256) dl[i] = dots[(size_t)b * HEADS * NTOK + i];
        __syncthreads();
        // 4 waves x 3 heads: shfl-only max & exp-sum (same per-head FP order as validated R3/R4)
        for (int hh = 0; hh < 3; hh++) {
            const int h = w * 3 + hh;
            const float* row = dl + h * NTOK;
            float m = -3.4e38f;
            for (int j = lane; j < NTOK; j += 64) m = fmaxf(m, row[j]);
            #pragma unroll
            for (int off = 32; off; off >>= 1) m = fmaxf(m, __shfl_xor(m, off));
            float s = 0.f;
            for (int j = lane; j < NTOK; j += 64) s += expf(row[j] - m);
            #pragma unroll
            for (int off = 32; off; off >>= 1) s += __shfl_xor(s, off);
            if (lane == 0) { sm.p3.mh[h] = m; sm.p3.sh[h] = s; }
        }
        __syncthreads();
        for (int p = tid; p < NPATCH; p += 256) {
            float ca = 0.f;
            #pragma unroll
            for (int h = 0; h < HEADS; h++)
                ca += expf(dl[h * NTOK + 1 + p] - sm.p3.mh[h]) / sm.p3.sh[h];
            ca *= (1.f / 12.f);
            out[O_CA + (size_t)b * NPATCH + p] = ca;
            sm.p3.vals[p] = __float_as_uint(ca);   // ca > 0 -> bit order == value order
        }
        __syncthreads();
        // rank: thread t < 192 owns patches 3t..3t+2 (contiguous for stable compaction)
        int f0 = 0, f1 = 0, f2 = 0;
        if (tid < 192) {
            const int p0 = 3 * tid;
            const unsigned int v0 = sm.p3.vals[p0], v1 = sm.p3.vals[p0 + 1], v2 = sm.p3.vals[p0 + 2];
            int r0 = 0, r1 = 0, r2 = 0;
            const uint4* v4 = reinterpret_cast<const uint4*>(sm.p3.vals);
            #pragma unroll 4
            for (int jb = 0; jb < NPATCH / 4; jb++) {
                const uint4 v = v4[jb];
                const int j = jb * 4;
                r0 += (v.x > v0) || (v.x == v0 && (j + 0) < p0);
                r0 += (v.y > v0) || (v.y == v0 && (j + 1) < p0);
                r0 += (v.z > v0) || (v.z == v0 && (j + 2) < p0);
                r0 += (v.w > v0) || (v.w == v0 && (j + 3) < p0);
                r1 += (v.x > v1) || (v.x == v1 && (j + 0) < p0 + 1);
                r1 += (v.y > v1) || (v.y == v1 && (j + 1) < p0 + 1);
                r1 += (v.z > v1) || (v.z == v1 && (j + 2) < p0 + 1);
                r1 += (v.w > v1) || (v.w == v1 && (j + 3) < p0 + 1);
                r2 += (v.x > v2) || (v.x == v2 && (j + 0) < p0 + 2);
                r2 += (v.y > v2) || (v.y == v2 && (j + 1) < p0 + 2);
                r2 += (v.z > v2) || (v.z == v2 && (j + 2) < p0 + 2);
                r2 += (v.w > v2) || (v.w == v2 && (j + 3) < p0 + 2);
            }
            f0 = (r0 < FT) ? 1 : 0;
            f1 = (r1 < FT) ? 1 : 0;
            f2 = (r2 < FT) ? 1 : 0;
        }
        // exclusive prefix over triples: wave shfl-scan + wave offsets
        const int l = f0 + f1 + f2;
        int scan = l;
        #pragma unroll
        for (int off = 1; off < 64; off <<= 1) {
            const int n = __shfl_up(scan, off);
            if (lane >= off) scan += n;
        }
        if (lane == 63) sm.p3.wsum[w] = scan;
        __syncthreads();
        int woff = 0;
        for (int i = 0; i < w; i++) woff += sm.p3.wsum[i];
        if (tid < 192) {
            int pos = woff + scan - l;
            const int p0 = 3 * tid;
            if (f0) { indw[b * FT + pos] = p0;     out[O_IND + (size_t)b * FT + pos] = (float)p0;       pos++; }
            if (f1) { indw[b * FT + pos] = p0 + 1; out[O_IND + (size_t)b * FT + pos] = (float)(p0 + 1); pos++; }
            if (f2) { indw[b * FT + pos] = p0 + 2; out[O_IND + (size_t)b * FT + pos] = (float)(p0 + 2); }
        }
        if (u == 0 && tid == 0 && write_ft) out[O_FT] = (float)FT;
    }
    grid_barrier(bar + 2);

    // ---------------- P4: index[b,t,c] = ind[b,t] broadcast over c ----------------
    {
        const int nf4 = 2482176;   // 9928704 / 4
        for (int f4 = u * 256 + tid; f4 < nf4; f4 += GRID * 256) {
            const int row = f4 / 192;              // 192 float4 per (b,t) row of 768
            const float v = (float)indw[row];
            float4 o; o.x = v; o.y = v; o.z = v; o.w = v;
            *reinterpret_cast<float4*>(out + O_INDEX + (size_t)f4 * 4) = o;
        }
    }
}

extern "C" void kernel_launch(void* const* d_in, const int* in_sizes, int n_in,
                              void* d_out, int out_size, void* d_ws, size_t ws_size,
                              hipStream_t stream) {
    const float* x  = (const float*)d_in[0];
    const float* W  = (const float*)d_in[2];   // W_qkv [768, 2304]
    const float* bq = (const float*)d_in[3];   // b_qkv [2304]
    float* ws = (float*)d_ws;
    float* out = (float*)d_out;
    const int write_ft = (out_size > (int)O_FT) ? 1 : 0;

    // zero the 3 barrier counters (ws is poisoned 0xAA before every timed launch)
    hipMemsetAsync((void*)(ws + WS_BAR), 0, 16, stream);
    k_all<<<GRID, 256, 0, stream>>>(x, W, bq, ws, out, write_ft);
}

// Round 7
// 423.440 us; speedup vs baseline: 1.2207x; 1.2207x over previous
//
#include <hip/hip_runtime.h>
#include <hip/hip_bf16.h>
#include <math.h>

#define BATCH 32
#define NTOK 577
#define NPATCH 576
#define CDIM 768
#define HEADS 12
#define DHEAD 64
#define W3 2304
#define FT 404
#define GRID 512   // 2 blocks/CU co-resident guaranteed (LDS 36.9K -> <=4/CU; VGPR 64)

// ---- workspace layout (float offsets) ----
#define WS_WTIL  24576      // 32*12*768
#define WS_DBIAS 319488     // 32*12
#define WS_DOTS  319872     // 32*12*577
#define WS_BAR   600000     // barrier counters (zeroed via tiny memset node)

// ---- output layout (FLOAT32 element offsets; d_out is float*) ----
#define O_X      0ULL           // 32*577*768 = 14180352
#define O_INDEX  14180352ULL    // 32*404*768 = 9928704
#define O_IND    24109056ULL    // 32*404
#define O_CA     24121984ULL    // 32*576
#define O_FT     24140416ULL

union SmemU {
    struct { float x0s[CDIM]; float red[256]; float qs[DHEAD]; } p1;      // 4.3 KB
    struct { float wt[HEADS * CDIM]; float db[HEADS]; } p2;               // 36.9 KB (max)
    struct { float dl[HEADS * NTOK]; float mh[HEADS]; float sh[HEADS];
             unsigned int vals[NPATCH]; int wsum[4]; int inds[FT]; } p3;  // 31.7 KB
};

// Grid barrier, cache-maintenance-minimal:
//  - arrive: RELEASE fetch_add (one L2 writeback per block — required anyway so
//    other XCDs can see this block's phase output)
//  - spin:   RELAXED agent loads (coherent-point read, NO per-poll L2 invalidate
//            — the per-poll ACQUIRE inv was R6's 95us/barrier pathology)
//  - depart: single ACQUIRE load (one L2 invalidate per block)
__device__ __forceinline__ void grid_barrier(unsigned* ctr) {
    __syncthreads();
    if (threadIdx.x == 0) {
        __hip_atomic_fetch_add(ctr, 1u, __ATOMIC_RELEASE, __HIP_MEMORY_SCOPE_AGENT);
        while (__hip_atomic_load(ctr, __ATOMIC_RELAXED, __HIP_MEMORY_SCOPE_AGENT) < GRID) {
            __builtin_amdgcn_s_sleep(2);
        }
        (void)__hip_atomic_load(ctr, __ATOMIC_ACQUIRE, __HIP_MEMORY_SCOPE_AGENT);
    }
    __syncthreads();
}

__global__ __launch_bounds__(256, 2) void k_all(const float* __restrict__ x,
                                                const float* __restrict__ W,
                                                const float* __restrict__ bias,
                                                float* __restrict__ ws,
                                                float* __restrict__ out,
                                                int write_ft) {
    __shared__ SmemU sm;
    const int u = blockIdx.x, tid = threadIdx.x;
    const int w = tid >> 6, lane = tid & 63;

    float* wtil  = ws + WS_WTIL;
    float* dbias = ws + WS_DBIAS;
    float* dots  = ws + WS_DOTS;
    unsigned* bar = (unsigned*)(ws + WS_BAR);

    // ---------------- P1: fold (q = x0·Wq + bq; wtil = q·Wk^T; dbias = q·bk) ----------------
    if (u < BATCH * HEADS) {
        const int b = u / HEADS, h = u % HEADS;
        for (int i = tid; i < CDIM; i += 256) sm.p1.x0s[i] = x[(size_t)b * NTOK * CDIM + i];
        __syncthreads();
        {
            const int d = tid & 63, seg = tid >> 6;
            const float* Wq = W + (size_t)(h * DHEAD + d);
            float acc = 0.f;
            const int c0 = seg * 192;
            #pragma unroll 8
            for (int c = c0; c < c0 + 192; c++)
                acc += sm.p1.x0s[c] * Wq[(size_t)c * W3];
            sm.p1.red[tid] = acc;
        }
        __syncthreads();
        if (tid < DHEAD) {
            float q = sm.p1.red[tid] + sm.p1.red[tid + 64] + sm.p1.red[tid + 128]
                    + sm.p1.red[tid + 192] + bias[h * DHEAD + tid];
            sm.p1.qs[tid] = q;
            float t = q * bias[CDIM + h * DHEAD + tid];
            #pragma unroll
            for (int off = 32; off; off >>= 1) t += __shfl_down(t, off);
            if (tid == 0) dbias[b * HEADS + h] = t;
        }
        __syncthreads();
        for (int c = tid; c < CDIM; c += 256) {
            const float* wr = W + (size_t)c * W3 + CDIM + h * DHEAD;
            float acc = 0.f;
            #pragma unroll
            for (int d = 0; d < DHEAD; d += 4) {
                float4 a = *reinterpret_cast<const float4*>(wr + d);
                acc += a.x * sm.p1.qs[d] + a.y * sm.p1.qs[d + 1]
                     + a.z * sm.p1.qs[d + 2] + a.w * sm.p1.qs[d + 3];
            }
            wtil[((size_t)b * HEADS + h) * CDIM + c] = acc;
        }
    }
    grid_barrier(bar + 0);

    // ---------------- P2: dots[b,h,j] + fused x -> out0 copy ----------------
    {
        const int b = u >> 4, c4 = (u & 15) * 4 + w;   // c4 in [0,64): token-slot within 64-stride
        for (int i = tid; i < HEADS * CDIM; i += 256) sm.p2.wt[i] = wtil[(size_t)b * HEADS * CDIM + i];
        if (tid < HEADS) sm.p2.db[tid] = dbias[b * HEADS + tid];
        __syncthreads();
        for (int it = 0; it < 10; it++) {
            const int j = it * 64 + c4;
            if (j >= NTOK) break;                       // j monotone in it
            const float4* xp = reinterpret_cast<const float4*>(x + ((size_t)b * NTOK + j) * CDIM);
            float4* op = reinterpret_cast<float4*>(out + O_X + ((size_t)b * NTOK + j) * CDIM);
            float acc[HEADS];
            #pragma unroll
            for (int h = 0; h < HEADS; h++) acc[h] = 0.f;
            #pragma unroll
            for (int i = 0; i < 3; i++) {
                float4 a = xp[i * 64 + lane];
                op[i * 64 + lane] = a;
                const int cbase = i * 256 + lane * 4;
                #pragma unroll
                for (int h = 0; h < HEADS; h++) {
                    float4 wv = *reinterpret_cast<const float4*>(&sm.p2.wt[h * CDIM + cbase]);
                    acc[h] += a.x * wv.x + a.y * wv.y + a.z * wv.z + a.w * wv.w;
                }
            }
            #pragma unroll
            for (int off = 32; off; off >>= 1)
                #pragma unroll
                for (int h = 0; h < HEADS; h++) acc[h] += __shfl_xor(acc[h], off);
            if (lane == 0) {
                #pragma unroll
                for (int h = 0; h < HEADS; h++)
                    dots[((size_t)b * HEADS + h) * NTOK + j] = 0.125f * (acc[h] + sm.p2.db[h]);
            }
        }
        __syncthreads();   // protect sm.p2 before union reuse
    }
    grid_barrier(bar + 1);

    // ---------------- P3 (32 blocks): softmax + ca + top-404 + compact + index bcast ----------------
    if (u < BATCH) {
        const int b = u;
        float* dl = sm.p3.dl;
        for (int i = tid; i < HEADS * NTOK; i += 256) dl[i] = dots[(size_t)b * HEADS * NTOK + i];
        __syncthreads();
        // 4 waves x 3 heads: shfl-only max & exp-sum (same per-head FP order as validated)
        for (int hh = 0; hh < 3; hh++) {
            const int h = w * 3 + hh;
            const float* row = dl + h * NTOK;
            float m = -3.4e38f;
            for (int j = lane; j < NTOK; j += 64) m = fmaxf(m, row[j]);
            #pragma unroll
            for (int off = 32; off; off >>= 1) m = fmaxf(m, __shfl_xor(m, off));
            float s = 0.f;
            for (int j = lane; j < NTOK; j += 64) s += expf(row[j] - m);
            #pragma unroll
            for (int off = 32; off; off >>= 1) s += __shfl_xor(s, off);
            if (lane == 0) { sm.p3.mh[h] = m; sm.p3.sh[h] = s; }
        }
        __syncthreads();
        for (int p = tid; p < NPATCH; p += 256) {
            float ca = 0.f;
            #pragma unroll
            for (int h = 0; h < HEADS; h++)
                ca += expf(dl[h * NTOK + 1 + p] - sm.p3.mh[h]) / sm.p3.sh[h];
            ca *= (1.f / 12.f);
            out[O_CA + (size_t)b * NPATCH + p] = ca;
            sm.p3.vals[p] = __float_as_uint(ca);   // ca > 0 -> bit order == value order
        }
        __syncthreads();
        // rank: thread t < 192 owns patches 3t..3t+2 (contiguous for stable compaction)
        int f0 = 0, f1 = 0, f2 = 0;
        if (tid < 192) {
            const int p0 = 3 * tid;
            const unsigned int v0 = sm.p3.vals[p0], v1 = sm.p3.vals[p0 + 1], v2 = sm.p3.vals[p0 + 2];
            int r0 = 0, r1 = 0, r2 = 0;
            const uint4* v4 = reinterpret_cast<const uint4*>(sm.p3.vals);
            #pragma unroll 4
            for (int jb = 0; jb < NPATCH / 4; jb++) {
                const uint4 v = v4[jb];
                const int j = jb * 4;
                r0 += (v.x > v0) || (v.x == v0 && (j + 0) < p0);
                r0 += (v.y > v0) || (v.y == v0 && (j + 1) < p0);
                r0 += (v.z > v0) || (v.z == v0 && (j + 2) < p0);
                r0 += (v.w > v0) || (v.w == v0 && (j + 3) < p0);
                r1 += (v.x > v1) || (v.x == v1 && (j + 0) < p0 + 1);
                r1 += (v.y > v1) || (v.y == v1 && (j + 1) < p0 + 1);
                r1 += (v.z > v1) || (v.z == v1 && (j + 2) < p0 + 1);
                r1 += (v.w > v1) || (v.w == v1 && (j + 3) < p0 + 1);
                r2 += (v.x > v2) || (v.x == v2 && (j + 0) < p0 + 2);
                r2 += (v.y > v2) || (v.y == v2 && (j + 1) < p0 + 2);
                r2 += (v.z > v2) || (v.z == v2 && (j + 2) < p0 + 2);
                r2 += (v.w > v2) || (v.w == v2 && (j + 3) < p0 + 2);
            }
            f0 = (r0 < FT) ? 1 : 0;
            f1 = (r1 < FT) ? 1 : 0;
            f2 = (r2 < FT) ? 1 : 0;
        }
        // exclusive prefix over triples: wave shfl-scan + wave offsets
        const int l = f0 + f1 + f2;
        int scan = l;
        #pragma unroll
        for (int off = 1; off < 64; off <<= 1) {
            const int n = __shfl_up(scan, off);
            if (lane >= off) scan += n;
        }
        if (lane == 63) sm.p3.wsum[w] = scan;
        __syncthreads();
        int woff = 0;
        for (int i = 0; i < w; i++) woff += sm.p3.wsum[i];
        if (tid < 192) {
            int pos = woff + scan - l;
            const int p0 = 3 * tid;
            if (f0) { sm.p3.inds[pos] = p0;     out[O_IND + (size_t)b * FT + pos] = (float)p0;       pos++; }
            if (f1) { sm.p3.inds[pos] = p0 + 1; out[O_IND + (size_t)b * FT + pos] = (float)(p0 + 1); pos++; }
            if (f2) { sm.p3.inds[pos] = p0 + 2; out[O_IND + (size_t)b * FT + pos] = (float)(p0 + 2); }
        }
        if (u == 0 && tid == 0 && write_ft) out[O_FT] = (float)FT;
        __syncthreads();
        // index broadcast for this batch: rows t of 768 floats, value inds[t]
        {
            float* obase = out + O_INDEX + (size_t)b * FT * CDIM;
            for (int t = w * 101; t < w * 101 + 101 && t < FT; t++) {
                const float v = (float)sm.p3.inds[t];
                float4 o; o.x = v; o.y = v; o.z = v; o.w = v;
                float4* orow = reinterpret_cast<float4*>(obase + (size_t)t * CDIM);
                orow[lane]       = o;
                orow[lane + 64]  = o;
                orow[lane + 128] = o;
            }
        }
    }
}

extern "C" void kernel_launch(void* const* d_in, const int* in_sizes, int n_in,
                              void* d_out, int out_size, void* d_ws, size_t ws_size,
                              hipStream_t stream) {
    const float* x  = (const float*)d_in[0];
    const float* W  = (const float*)d_in[2];   // W_qkv [768, 2304]
    const float* bq = (const float*)d_in[3];   // b_qkv [2304]
    float* ws = (float*)d_ws;
    float* out = (float*)d_out;
    const int write_ft = (out_size > (int)O_FT) ? 1 : 0;

    // zero the barrier counters (ws is poisoned 0xAA before every timed launch)
    hipMemsetAsync((void*)(ws + WS_BAR), 0, 16, stream);
    k_all<<<GRID, 256, 0, stream>>>(x, W, bq, ws, out, write_ft);
}